// Round 7
// baseline (740.829 us; speedup 1.0000x reference)
//
#include <hip/hip_runtime.h>

// GCNConv forward: bucketed edge binning + fused LDS-accumulate gather.
// t[i] = bf16( dis[i]*(x@W)[i] );  out[c] = b + dis[c]*( t[c] + sum_{edges r->c} t[r] )
// dis[i] = rsqrt(cnt[i]+1), cnt = in-degree over targets.
//
// Fast path: memset -> hist2 (flat cnt + bucket hist) -> bscan -> bscatter (bin edges
// by 64-col bucket) -> gemm (t) -> fused_gather (per-bucket LDS fp32 accumulate).

#define D 64
#define BSH 6            // 64 cols per bucket
#define BCOLS 64
#define MAXNB 2048       // supports n <= 131072
#define BM 128           // GEMM rows per block
#define NBLK3 512        // bscatter blocks
#define OPAD 68          // LDS out tile stride (randomizes banks via lc*4)

__device__ inline unsigned short f2bf(float f) {   // RNE fp32 -> bf16
    unsigned u = __float_as_uint(f);
    return (unsigned short)((u + 0x7FFFu + ((u >> 16) & 1u)) >> 16);
}

// ---------- fast path ----------

// One pass over col: flat per-col count (global atomics, L2-resident) + per-bucket hist.
__global__ __launch_bounds__(256) void hist2_kernel(const int* __restrict__ col, int* __restrict__ cnt,
                                                    int* __restrict__ bcnt, int e, int nb) {
    __shared__ int h[MAXNB];
    int tid = threadIdx.x;
    for (int i = tid; i < nb; i += 256) h[i] = 0;
    __syncthreads();
    int stride = gridDim.x * 256;
    for (int i = blockIdx.x * 256 + tid; i < e; i += stride) {
        int c = col[i];
        atomicAdd(&cnt[c], 1);
        atomicAdd(&h[c >> BSH], 1);
    }
    __syncthreads();
    for (int i = tid; i < nb; i += 256)
        if (h[i]) atomicAdd(&bcnt[i], h[i]);
}

// Exclusive scan of bcnt (nb <= 2048, 2 elems/thread) -> base, cur. base[nb] = e.
__global__ __launch_bounds__(1024) void bscan_kernel(const int* __restrict__ bcnt, int* __restrict__ base,
                                                     int* __restrict__ cur, int nb, int e) {
    __shared__ int s[1024];
    int tid = threadIdx.x;
    int i0 = 2 * tid, i1 = 2 * tid + 1;
    int v0 = (i0 < nb) ? bcnt[i0] : 0;
    int v1 = (i1 < nb) ? bcnt[i1] : 0;
    s[tid] = v0 + v1;
    __syncthreads();
#pragma unroll
    for (int d = 1; d < 1024; d <<= 1) {
        int add = (tid >= d) ? s[tid - d] : 0;
        __syncthreads();
        s[tid] += add;
        __syncthreads();
    }
    int ex = s[tid] - v0 - v1;
    if (i0 < nb) { base[i0] = ex;      cur[i0] = ex; }
    if (i1 < nb) { base[i1] = ex + v0; cur[i1] = ex + v0; }
    if (tid == 0) base[nb] = e;
}

// Bucket-grouped packed edges: binned[pos] = ((col&63) << 20) | row   (row < 2^20)
__global__ __launch_bounds__(256) void bscatter_kernel(const int* __restrict__ row, const int* __restrict__ col,
                                                       int* __restrict__ bcur, unsigned int* __restrict__ binned,
                                                       int e, int nb, int chunk) {
    __shared__ int h[MAXNB];
    __shared__ int res[MAXNB];
    int tid = threadIdx.x;
    for (int i = tid; i < nb; i += 256) h[i] = 0;
    __syncthreads();
    int i0 = blockIdx.x * chunk;
    int i1 = i0 + chunk; if (i1 > e) i1 = e;
    for (int i = i0 + tid; i < i1; i += 256)
        atomicAdd(&h[col[i] >> BSH], 1);
    __syncthreads();
    for (int b = tid; b < nb; b += 256) {
        int c = h[b];
        res[b] = c ? atomicAdd(&bcur[b], c) : 0;
        h[b] = 0;  // reuse as local cursor
    }
    __syncthreads();
    for (int i = i0 + tid; i < i1; i += 256) {
        int cl = col[i];
        int b = cl >> BSH;
        int pos = res[b] + atomicAdd(&h[b], 1);
        binned[pos] = ((unsigned int)(cl & (BCOLS - 1)) << 20) | (unsigned int)row[i];
    }
}

// t = bf16( rsqrt(cnt+1) * (x @ W) ): register-tiled fp32 GEMM.
__global__ __launch_bounds__(256) void xw_t_gemm_cnt_kernel(const float* __restrict__ x, const float* __restrict__ W,
                                                            const int* __restrict__ cnt,
                                                            unsigned short* __restrict__ t, int n) {
    __shared__ float xT[D][BM];   // [k][row], 32 KB
    __shared__ float Wl[D][D];    // [k][col], 16 KB
    int tid = threadIdx.x;
    int r0 = blockIdx.x * BM;

    {
        const float4* Wv = (const float4*)W;
        float4* Wd = (float4*)&Wl[0][0];
#pragma unroll
        for (int j = 0; j < 4; ++j) Wd[j * 256 + tid] = Wv[j * 256 + tid];
    }
    {
        int row = tid >> 1;
        int c0 = (tid & 1) * 32;
        int gr = r0 + row;
        if (gr < n) {
            const float4* xv = (const float4*)(x + (size_t)gr * D + c0);
#pragma unroll
            for (int j = 0; j < 8; ++j) {
                float4 v = xv[j];
                int c = c0 + j * 4;
                xT[c + 0][row] = v.x;
                xT[c + 1][row] = v.y;
                xT[c + 2][row] = v.z;
                xT[c + 3][row] = v.w;
            }
        }
    }
    __syncthreads();

    int cg = tid & 15;
    int rg = tid >> 4;
    float acc[8][4];
#pragma unroll
    for (int i = 0; i < 8; ++i)
#pragma unroll
        for (int j = 0; j < 4; ++j) acc[i][j] = 0.0f;

#pragma unroll 8
    for (int k = 0; k < D; ++k) {
        float4 xa = *(const float4*)&xT[k][rg * 8];
        float4 xb = *(const float4*)&xT[k][rg * 8 + 4];
        float4 wv = *(const float4*)&Wl[k][cg * 4];
        float xr[8] = {xa.x, xa.y, xa.z, xa.w, xb.x, xb.y, xb.z, xb.w};
        float wr[4] = {wv.x, wv.y, wv.z, wv.w};
#pragma unroll
        for (int i = 0; i < 8; ++i)
#pragma unroll
            for (int j = 0; j < 4; ++j) acc[i][j] += xr[i] * wr[j];
    }

#pragma unroll
    for (int i = 0; i < 8; ++i) {
        int gr = r0 + rg * 8 + i;
        if (gr < n) {
            float dsc = rsqrtf((float)(cnt[gr] + 1));
            ushort4 o;
            o.x = f2bf(acc[i][0] * dsc); o.y = f2bf(acc[i][1] * dsc);
            o.z = f2bf(acc[i][2] * dsc); o.w = f2bf(acc[i][3] * dsc);
            *(ushort4*)(t + (size_t)gr * D + cg * 4) = o;
        }
    }
}

// One block per 64-col bucket: stream binned edges, gather t rows (8-edge x 8-lane
// subgroups), ds_add_f32 into LDS tile o[64][OPAD]; epilogue adds self-loop + bias.
__global__ __launch_bounds__(256) void fused_gather_kernel(const int* __restrict__ base,
                                                           const unsigned int* __restrict__ binned,
                                                           const int* __restrict__ cnt,
                                                           const unsigned short* __restrict__ t,
                                                           const float* __restrict__ b,
                                                           float* __restrict__ out, int n) {
    __shared__ float o[BCOLS * OPAD];
    int tid = threadIdx.x;
    int bk = blockIdx.x;
    int s0 = base[bk], s1 = base[bk + 1];

    for (int i = tid; i < BCOLS * OPAD; i += 256) o[i] = 0.0f;
    __syncthreads();

    int w  = tid >> 6;          // wave 0..3
    int e8 = (tid & 63) >> 3;   // edge subgroup 0..7
    int d8 = tid & 7;           // 16B chunk of row

    for (int j = s0 + w * 16; j < s1; j += 64) {
        int i0 = j + e8;
        int i1 = j + 8 + e8;
        bool p0 = i0 < s1;
        bool p1 = i1 < s1;
        unsigned v0 = 0, v1 = 0;
        uint4 u0 = {0, 0, 0, 0}, u1 = {0, 0, 0, 0};
        int lc0 = 0, lc1 = 0;
        if (p0) {
            v0 = binned[i0];
            lc0 = (v0 >> 20) & (BCOLS - 1);
            u0 = *(const uint4*)(t + (((size_t)(v0 & 0xFFFFFu)) << 6) + d8 * 8);
        }
        if (p1) {
            v1 = binned[i1];
            lc1 = (v1 >> 20) & (BCOLS - 1);
            u1 = *(const uint4*)(t + (((size_t)(v1 & 0xFFFFFu)) << 6) + d8 * 8);
        }
        if (p0) {
            float* dst = o + lc0 * OPAD + d8 * 8;
            atomicAdd(dst + 0, __uint_as_float(u0.x << 16));
            atomicAdd(dst + 1, __uint_as_float(u0.x & 0xFFFF0000u));
            atomicAdd(dst + 2, __uint_as_float(u0.y << 16));
            atomicAdd(dst + 3, __uint_as_float(u0.y & 0xFFFF0000u));
            atomicAdd(dst + 4, __uint_as_float(u0.z << 16));
            atomicAdd(dst + 5, __uint_as_float(u0.z & 0xFFFF0000u));
            atomicAdd(dst + 6, __uint_as_float(u0.w << 16));
            atomicAdd(dst + 7, __uint_as_float(u0.w & 0xFFFF0000u));
        }
        if (p1) {
            float* dst = o + lc1 * OPAD + d8 * 8;
            atomicAdd(dst + 0, __uint_as_float(u1.x << 16));
            atomicAdd(dst + 1, __uint_as_float(u1.x & 0xFFFF0000u));
            atomicAdd(dst + 2, __uint_as_float(u1.y << 16));
            atomicAdd(dst + 3, __uint_as_float(u1.y & 0xFFFF0000u));
            atomicAdd(dst + 4, __uint_as_float(u1.z << 16));
            atomicAdd(dst + 5, __uint_as_float(u1.z & 0xFFFF0000u));
            atomicAdd(dst + 6, __uint_as_float(u1.w << 16));
            atomicAdd(dst + 7, __uint_as_float(u1.w & 0xFFFF0000u));
        }
    }
    __syncthreads();

    // epilogue: 4 threads per col, 16 dims each
    int lc = tid >> 2;
    int q4 = (tid & 3) * 16;
    int c = (bk << BSH) + lc;
    if (c < n) {
        float dsc = rsqrtf((float)(cnt[c] + 1));
        const uint4* ts = (const uint4*)(t + ((size_t)c << 6) + q4);
        uint4 sa = ts[0], sb = ts[1];
        float self[16];
        self[0]  = __uint_as_float(sa.x << 16); self[1]  = __uint_as_float(sa.x & 0xFFFF0000u);
        self[2]  = __uint_as_float(sa.y << 16); self[3]  = __uint_as_float(sa.y & 0xFFFF0000u);
        self[4]  = __uint_as_float(sa.z << 16); self[5]  = __uint_as_float(sa.z & 0xFFFF0000u);
        self[6]  = __uint_as_float(sa.w << 16); self[7]  = __uint_as_float(sa.w & 0xFFFF0000u);
        self[8]  = __uint_as_float(sb.x << 16); self[9]  = __uint_as_float(sb.x & 0xFFFF0000u);
        self[10] = __uint_as_float(sb.y << 16); self[11] = __uint_as_float(sb.y & 0xFFFF0000u);
        self[12] = __uint_as_float(sb.z << 16); self[13] = __uint_as_float(sb.z & 0xFFFF0000u);
        self[14] = __uint_as_float(sb.w << 16); self[15] = __uint_as_float(sb.w & 0xFFFF0000u);
        const float* lrow = o + lc * OPAD + q4;
        float* op = out + (size_t)c * D + q4;
#pragma unroll
        for (int g = 0; g < 4; ++g) {
            float4 r;
            r.x = b[q4 + g * 4 + 0] + dsc * (lrow[g * 4 + 0] + self[g * 4 + 0]);
            r.y = b[q4 + g * 4 + 1] + dsc * (lrow[g * 4 + 1] + self[g * 4 + 1]);
            r.z = b[q4 + g * 4 + 2] + dsc * (lrow[g * 4 + 2] + self[g * 4 + 2]);
            r.w = b[q4 + g * 4 + 3] + dsc * (lrow[g * 4 + 3] + self[g * 4 + 3]);
            *(float4*)(op + g * 4) = r;
        }
    }
}

// ---------- mid fallback: flat hist/scan/fill CSR + gather8 (round-6 proven) ----------

__global__ __launch_bounds__(256) void cnt_init_kernel(int* __restrict__ cnt, int n) {
    int i = blockIdx.x * 256 + threadIdx.x;
    if (i < n) cnt[i] = 0;
}
__global__ __launch_bounds__(256) void hist_kernel(const int* __restrict__ col, int* __restrict__ cnt, int e) {
    int i = blockIdx.x * 256 + threadIdx.x;
    if (i < e) atomicAdd(&cnt[col[i]], 1);
}
__global__ __launch_bounds__(1024) void scan1_kernel(const int* __restrict__ cnt, float* __restrict__ dis,
                                                     int* __restrict__ off, int* __restrict__ bsum, int n) {
    __shared__ int s[1024];
    int tid = threadIdx.x;
    int i = blockIdx.x * 1024 + tid;
    int v = (i < n) ? cnt[i] : 0;
    if (i < n) dis[i] = rsqrtf((float)(v + 1));
    s[tid] = v;
    __syncthreads();
#pragma unroll
    for (int d = 1; d < 1024; d <<= 1) {
        int add = (tid >= d) ? s[tid - d] : 0;
        __syncthreads();
        s[tid] += add;
        __syncthreads();
    }
    int incl = s[tid];
    if (i < n) off[i] = incl - v;
    if (tid == 1023) bsum[blockIdx.x] = incl;
}
__global__ __launch_bounds__(1024) void scan2_kernel(int* __restrict__ bsum, int nb) {
    __shared__ int s[1024];
    int tid = threadIdx.x;
    int v = (tid < nb) ? bsum[tid] : 0;
    s[tid] = v;
    __syncthreads();
#pragma unroll
    for (int d = 1; d < 1024; d <<= 1) {
        int add = (tid >= d) ? s[tid - d] : 0;
        __syncthreads();
        s[tid] += add;
        __syncthreads();
    }
    if (tid < nb) bsum[tid] = s[tid] - v;
}
__global__ __launch_bounds__(1024) void scan3_kernel(int* __restrict__ off, const int* __restrict__ bsum,
                                                     int* __restrict__ cur, int n) {
    int i = blockIdx.x * 1024 + threadIdx.x;
    if (i < n) {
        int o = off[i] + bsum[blockIdx.x];
        off[i] = o;
        cur[i] = o;
    }
}
__global__ __launch_bounds__(256) void fill_kernel(const int* __restrict__ row, const int* __restrict__ col,
                                                   int* __restrict__ cur, int* __restrict__ srcs, int e) {
    int i = blockIdx.x * 256 + threadIdx.x;
    if (i < e) {
        int pos = atomicAdd(&cur[col[i]], 1);
        srcs[pos] = row[i];
    }
}
__global__ __launch_bounds__(256) void xw_t_gemm_kernel(const float* __restrict__ x, const float* __restrict__ W,
                                                        const float* __restrict__ dis,
                                                        unsigned short* __restrict__ t, int n) {
    __shared__ float xT[D][BM];
    __shared__ float Wl[D][D];
    int tid = threadIdx.x;
    int r0 = blockIdx.x * BM;
    {
        const float4* Wv = (const float4*)W;
        float4* Wd = (float4*)&Wl[0][0];
#pragma unroll
        for (int j = 0; j < 4; ++j) Wd[j * 256 + tid] = Wv[j * 256 + tid];
    }
    {
        int row = tid >> 1;
        int c0 = (tid & 1) * 32;
        int gr = r0 + row;
        if (gr < n) {
            const float4* xv = (const float4*)(x + (size_t)gr * D + c0);
#pragma unroll
            for (int j = 0; j < 8; ++j) {
                float4 v = xv[j];
                int c = c0 + j * 4;
                xT[c + 0][row] = v.x; xT[c + 1][row] = v.y;
                xT[c + 2][row] = v.z; xT[c + 3][row] = v.w;
            }
        }
    }
    __syncthreads();
    int cg = tid & 15;
    int rg = tid >> 4;
    float acc[8][4];
#pragma unroll
    for (int i = 0; i < 8; ++i)
#pragma unroll
        for (int j = 0; j < 4; ++j) acc[i][j] = 0.0f;
#pragma unroll 8
    for (int k = 0; k < D; ++k) {
        float4 xa = *(const float4*)&xT[k][rg * 8];
        float4 xb = *(const float4*)&xT[k][rg * 8 + 4];
        float4 wv = *(const float4*)&Wl[k][cg * 4];
        float xr[8] = {xa.x, xa.y, xa.z, xa.w, xb.x, xb.y, xb.z, xb.w};
        float wr[4] = {wv.x, wv.y, wv.z, wv.w};
#pragma unroll
        for (int i = 0; i < 8; ++i)
#pragma unroll
            for (int j = 0; j < 4; ++j) acc[i][j] += xr[i] * wr[j];
    }
#pragma unroll
    for (int i = 0; i < 8; ++i) {
        int gr = r0 + rg * 8 + i;
        if (gr < n) {
            float dsc = dis[gr];
            ushort4 o;
            o.x = f2bf(acc[i][0] * dsc); o.y = f2bf(acc[i][1] * dsc);
            o.z = f2bf(acc[i][2] * dsc); o.w = f2bf(acc[i][3] * dsc);
            *(ushort4*)(t + (size_t)gr * D + cg * 4) = o;
        }
    }
}
__device__ inline void add8(float* acc, uint4 u) {
    acc[0] += __uint_as_float(u.x << 16);
    acc[1] += __uint_as_float(u.x & 0xFFFF0000u);
    acc[2] += __uint_as_float(u.y << 16);
    acc[3] += __uint_as_float(u.y & 0xFFFF0000u);
    acc[4] += __uint_as_float(u.z << 16);
    acc[5] += __uint_as_float(u.z & 0xFFFF0000u);
    acc[6] += __uint_as_float(u.w << 16);
    acc[7] += __uint_as_float(u.w & 0xFFFF0000u);
}
__global__ __launch_bounds__(256) void gather8_kernel(const int* __restrict__ off, const int* __restrict__ end,
                                                      const int* __restrict__ srcs,
                                                      const unsigned short* __restrict__ t,
                                                      const float* __restrict__ dis, const float* __restrict__ b,
                                                      float* __restrict__ out, int n) {
    int c    = blockIdx.x * 4 + (threadIdx.x >> 6);
    int lane = threadIdx.x & 63;
    if (c >= n) return;
    int e8 = lane >> 3;
    int d8 = lane & 7;
    int j0 = off[c];
    int jend = end[c];
    float acc[8];
#pragma unroll
    for (int q = 0; q < 8; ++q) acc[q] = 0.0f;
    if (e8 == 0) {
        uint4 u = *(const uint4*)(t + (size_t)c * D + d8 * 8);
        add8(acc, u);
    }
    for (int jb = j0; jb < jend; jb += 64) {
        int m = jend - jb; if (m > 64) m = 64;
        int sv = (jb + lane < jend) ? srcs[jb + lane] : 0;
        int k = 0;
        for (; k + 16 <= m; k += 16) {
            int r0 = __shfl(sv, k + e8);
            int r1 = __shfl(sv, k + 8 + e8);
            uint4 u0 = *(const uint4*)(t + (size_t)r0 * D + d8 * 8);
            uint4 u1 = *(const uint4*)(t + (size_t)r1 * D + d8 * 8);
            add8(acc, u0);
            add8(acc, u1);
        }
        for (; k < m; k += 8) {
            int idx = k + e8;
            int r = __shfl(sv, idx);
            if (idx < m) {
                uint4 u = *(const uint4*)(t + (size_t)r * D + d8 * 8);
                add8(acc, u);
            }
        }
    }
#pragma unroll
    for (int s = 8; s < 64; s <<= 1)
#pragma unroll
        for (int q = 0; q < 8; ++q) acc[q] += __shfl_xor(acc[q], s);
    if (e8 == 0) {
        float dsc = dis[c];
        float* op = out + (size_t)c * D + d8 * 8;
        const float* bp = b + d8 * 8;
        float4 o0, o1;
        o0.x = bp[0] + dsc * acc[0]; o0.y = bp[1] + dsc * acc[1];
        o0.z = bp[2] + dsc * acc[2]; o0.w = bp[3] + dsc * acc[3];
        o1.x = bp[4] + dsc * acc[4]; o1.y = bp[5] + dsc * acc[5];
        o1.z = bp[6] + dsc * acc[6]; o1.w = bp[7] + dsc * acc[7];
        *(float4*)op = o0;
        *(float4*)(op + 4) = o1;
    }
}

// ---------- last fallback: atomic scatter ----------

__global__ __launch_bounds__(256) void deg_init_kernel(float* __restrict__ deg, int n) {
    int i = blockIdx.x * 256 + threadIdx.x;
    if (i < n) deg[i] = 1.0f;
}
__global__ __launch_bounds__(256) void deg_count_kernel(const int* __restrict__ col, float* __restrict__ deg, int e) {
    int i = blockIdx.x * 256 + threadIdx.x;
    if (i < e) atomicAdd(&deg[col[i]], 1.0f);
}
__global__ __launch_bounds__(256) void deg_rsqrt_kernel(float* __restrict__ deg, int n) {
    int i = blockIdx.x * 256 + threadIdx.x;
    if (i < n) deg[i] = rsqrtf(deg[i]);
}
__global__ __launch_bounds__(256) void xw_kernel(const float* __restrict__ x, const float* __restrict__ W,
                                                 float* __restrict__ xw, int n) {
    __shared__ float Wl[D * D];
    int tid = threadIdx.x;
    for (int i = tid; i < D * D; i += 256) Wl[i] = W[i];
    __syncthreads();
    int lane = tid & 63;
    int row  = blockIdx.x * 4 + (tid >> 6);
    if (row >= n) return;
    float xv = x[(size_t)row * D + lane];
    float acc = 0.0f;
#pragma unroll
    for (int k = 0; k < D; ++k) acc += __shfl(xv, k) * Wl[k * D + lane];
    xw[(size_t)row * D + lane] = acc;
}
__global__ __launch_bounds__(256) void out_init_kernel(const float* __restrict__ xw, const float* __restrict__ dis,
                                                       const float* __restrict__ b, float* __restrict__ out, int n) {
    int i = blockIdx.x * 256 + threadIdx.x;
    if (i < n * D) {
        int node = i >> 6;
        float d = dis[node];
        out[i] = b[i & 63] + d * d * xw[i];
    }
}
__global__ __launch_bounds__(256) void scatter_kernel(const int* __restrict__ row, const int* __restrict__ col,
                                                      const float* __restrict__ dis, const float* __restrict__ xw,
                                                      float* __restrict__ out, int e) {
    int idx  = blockIdx.x * 4 + (threadIdx.x >> 6);
    int lane = threadIdx.x & 63;
    if (idx >= e) return;
    int r = row[idx], c = col[idx];
    float w = dis[r] * dis[c];
    atomicAdd(&out[(size_t)c * D + lane], w * xw[(size_t)r * D + lane]);
}

// ---------- launch ----------

extern "C" void kernel_launch(void* const* d_in, const int* in_sizes, int n_in,
                              void* d_out, int out_size, void* d_ws, size_t ws_size,
                              hipStream_t stream) {
    const float* x  = (const float*)d_in[0];
    const int*   ei = (const int*)d_in[1];
    const float* W  = (const float*)d_in[2];
    const float* b  = (const float*)d_in[3];
    float*       out = (float*)d_out;

    int n = in_sizes[0] / D;   // 100000
    int e = in_sizes[1] / 2;   // 1600000
    const int* row = ei;
    const int* col = ei + e;

    size_t nA = ((size_t)n + 255) & ~(size_t)255;
    int nb = (n + BCOLS - 1) >> BSH;

    // fast: cnt[nA] bcnt[2048] base[2056] bcur[2048] (int) | t[nA*D] (bf16) | binned[e]
    size_t fast_needed = (nA + 2048 + 2056 + 2048) * 4 + nA * D * 2 + (size_t)e * 4;
    // mid:  cnt[nA] off[nA] cur[nA] bsum[1024] | dis[nA] | t[nA*D] bf16 | srcs[e]
    size_t mid_needed  = (3 * nA + 1024) * 4 + nA * 4 + nA * D * 2 + (size_t)e * 4;

    if (n <= 131072 && nb <= MAXNB && ws_size >= fast_needed) {
        int*   cnt    = (int*)d_ws;
        int*   bcnt   = cnt + nA;
        int*   base   = bcnt + 2048;
        int*   bcur   = base + 2056;
        unsigned short* t = (unsigned short*)(bcur + 2048);
        unsigned int* binned = (unsigned int*)(t + nA * D);

        int chunk = (e + NBLK3 - 1) / NBLK3;

        hipMemsetAsync(cnt, 0, (nA + 2048) * 4, stream);  // cnt + bcnt
        hist2_kernel<<<256, 256, 0, stream>>>(col, cnt, bcnt, e, nb);
        bscan_kernel<<<1, 1024, 0, stream>>>(bcnt, base, bcur, nb, e);
        bscatter_kernel<<<NBLK3, 256, 0, stream>>>(row, col, bcur, binned, e, nb, chunk);
        xw_t_gemm_cnt_kernel<<<(n + BM - 1) / BM, 256, 0, stream>>>(x, W, cnt, t, n);
        fused_gather_kernel<<<nb, 256, 0, stream>>>(base, binned, cnt, t, b, out, n);
    } else if (ws_size >= mid_needed) {
        int*   cnt  = (int*)d_ws;
        int*   off  = cnt + nA;
        int*   cur  = off + nA;
        int*   bsum = cur + nA;
        float* dis  = (float*)(bsum + 1024);
        unsigned short* t = (unsigned short*)(dis + nA);
        int*   srcs = (int*)(t + nA * D);

        int nblk = (n + 1023) / 1024;
        cnt_init_kernel<<<(n + 255) / 256, 256, 0, stream>>>(cnt, n);
        hist_kernel<<<(e + 255) / 256, 256, 0, stream>>>(col, cnt, e);
        scan1_kernel<<<nblk, 1024, 0, stream>>>(cnt, dis, off, bsum, n);
        scan2_kernel<<<1, 1024, 0, stream>>>(bsum, nblk);
        scan3_kernel<<<nblk, 1024, 0, stream>>>(off, bsum, cur, n);
        xw_t_gemm_kernel<<<(n + BM - 1) / BM, 256, 0, stream>>>(x, W, dis, t, n);
        fill_kernel<<<(e + 255) / 256, 256, 0, stream>>>(row, col, cur, srcs, e);
        gather8_kernel<<<(n + 3) / 4, 256, 0, stream>>>(off, cur, srcs, t, dis, b, out, n);
    } else {
        float* deg = (float*)d_ws;
        float* xw  = deg + nA;
        deg_init_kernel<<<(n + 255) / 256, 256, 0, stream>>>(deg, n);
        deg_count_kernel<<<(e + 255) / 256, 256, 0, stream>>>(col, deg, e);
        deg_rsqrt_kernel<<<(n + 255) / 256, 256, 0, stream>>>(deg, n);
        xw_kernel<<<(n + 3) / 4, 256, 0, stream>>>(x, W, xw, n);
        out_init_kernel<<<((size_t)n * D + 255) / 256, 256, 0, stream>>>(xw, deg, b, out, n);
        scatter_kernel<<<(e + 3) / 4, 256, 0, stream>>>(row, col, deg, xw, out, e);
    }
}

// Round 8
// 124.472 us; speedup vs baseline: 5.9517x; 5.9517x over previous
//
#include <hip/hip_runtime.h>

// GCNConv forward via bucketed on-device CSR build + bf16 register gather.
// t[i] = bf16( dis[i]*(x@W)[i] );  out[c] = b + dis[c]*( t[c] + sum_{edges r->c} t[r] )

#define D 64
#define BSH 7            // bucket shift: 128 cols per bucket
#define BCOLS 128
#define MAXNB 1024       // supports n <= 131072 (row fits in 20 bits)
#define BM 128           // GEMM rows per block
#define NBLK3 512        // bscatter blocks

__device__ inline unsigned short f2bf(float f) {   // RNE fp32 -> bf16
    unsigned u = __float_as_uint(f);
    return (unsigned short)((u + 0x7FFFu + ((u >> 16) & 1u)) >> 16);
}

// ---------- fast path: bucketed CSR build ----------

__global__ __launch_bounds__(256) void bhist_kernel(const int* __restrict__ col, int* __restrict__ bcnt,
                                                    int e, int nb) {
    __shared__ int h[MAXNB];
    int tid = threadIdx.x;
    for (int i = tid; i < nb; i += 256) h[i] = 0;
    __syncthreads();
    int stride = gridDim.x * 256;
    for (int i = blockIdx.x * 256 + tid; i < e; i += stride)
        atomicAdd(&h[col[i] >> BSH], 1);
    __syncthreads();
    for (int i = tid; i < nb; i += 256)
        if (h[i]) atomicAdd(&bcnt[i], h[i]);
}

// Bucket-grouped packed edges: binned[pos] = ((col&127) << 20) | row.
// Each block recomputes the exclusive scan of bcnt in LDS (saves the bscan launch);
// global cursor bcur starts at 0; block 0 publishes base[] for bucket_build.
__global__ __launch_bounds__(256) void bscatter_kernel(const int* __restrict__ row, const int* __restrict__ col,
                                                       const int* __restrict__ bcnt, int* __restrict__ bcur,
                                                       int* __restrict__ base, unsigned int* __restrict__ binned,
                                                       int e, int nb, int chunk) {
    __shared__ int sc[MAXNB];   // exclusive scan of bcnt
    __shared__ int ws[256];
    __shared__ int h[MAXNB];
    __shared__ int res[MAXNB];
    int tid = threadIdx.x;

    // 4 elems per thread exclusive scan of bcnt[0..nb)
    int t4 = tid * 4;
    int a0 = (t4 + 0 < nb) ? bcnt[t4 + 0] : 0;
    int a1 = (t4 + 1 < nb) ? bcnt[t4 + 1] : 0;
    int a2 = (t4 + 2 < nb) ? bcnt[t4 + 2] : 0;
    int a3 = (t4 + 3 < nb) ? bcnt[t4 + 3] : 0;
    int s = a0 + a1 + a2 + a3;
    ws[tid] = s;
    __syncthreads();
#pragma unroll
    for (int d = 1; d < 256; d <<= 1) {
        int add = (tid >= d) ? ws[tid - d] : 0;
        __syncthreads();
        ws[tid] += add;
        __syncthreads();
    }
    int ex = ws[tid] - s;
    if (t4 + 0 < MAXNB) sc[t4 + 0] = ex;
    if (t4 + 1 < MAXNB) sc[t4 + 1] = ex + a0;
    if (t4 + 2 < MAXNB) sc[t4 + 2] = ex + a0 + a1;
    if (t4 + 3 < MAXNB) sc[t4 + 3] = ex + a0 + a1 + a2;
    for (int i = tid; i < nb; i += 256) h[i] = 0;
    __syncthreads();

    if (blockIdx.x == 0) {  // publish for bucket_build (launched after)
        for (int i = tid; i < nb; i += 256) base[i] = sc[i];
        if (tid == 0) base[nb] = e;
    }

    int i0 = blockIdx.x * chunk;
    int i1 = i0 + chunk; if (i1 > e) i1 = e;
    for (int i = i0 + tid; i < i1; i += 256)
        atomicAdd(&h[col[i] >> BSH], 1);
    __syncthreads();
    for (int b = tid; b < nb; b += 256) {
        int c = h[b];
        res[b] = c ? (sc[b] + atomicAdd(&bcur[b], c)) : 0;
        h[b] = 0;  // reuse as local cursor
    }
    __syncthreads();
    for (int i = i0 + tid; i < i1; i += 256) {
        int cl = col[i];
        int b = cl >> BSH;
        int pos = res[b] + atomicAdd(&h[b], 1);
        binned[pos] = ((unsigned int)(cl & (BCOLS - 1)) << 20) | (unsigned int)row[i];
    }
}

__global__ __launch_bounds__(256) void bucket_build_kernel(const int* __restrict__ base,
                                                           const unsigned int* __restrict__ binned,
                                                           int* __restrict__ off, int* __restrict__ end,
                                                           float* __restrict__ dis, int* __restrict__ srcs,
                                                           int n) {
    __shared__ int hc[BCOLS];
    __shared__ int ho[BCOLS];
    __shared__ int hcur[BCOLS];
    int tid = threadIdx.x;
    int b = blockIdx.x;
    int s0 = base[b], s1 = base[b + 1];
    if (tid < BCOLS) hc[tid] = 0;
    __syncthreads();
    for (int i = s0 + tid; i < s1; i += 256)
        atomicAdd(&hc[binned[i] >> 20], 1);
    __syncthreads();
    if (tid < BCOLS) ho[tid] = hc[tid];
    __syncthreads();
#pragma unroll
    for (int d = 1; d < BCOLS; d <<= 1) {
        int add = (tid < BCOLS && tid >= d) ? ho[tid - d] : 0;
        __syncthreads();
        if (tid < BCOLS) ho[tid] += add;
        __syncthreads();
    }
    if (tid < BCOLS) {
        int col = (b << BSH) + tid;
        if (col < n) {
            int ex = ho[tid] - hc[tid];
            off[col] = s0 + ex;
            end[col] = s0 + ho[tid];
            dis[col] = rsqrtf((float)(hc[tid] + 1));  // +1 self loop
            hcur[tid] = s0 + ex;
        }
    }
    __syncthreads();
    for (int i = s0 + tid; i < s1; i += 256) {
        unsigned int v = binned[i];
        int lc = v >> 20;
        int pos = atomicAdd(&hcur[lc], 1);
        srcs[pos] = (int)(v & 0xFFFFFu);
    }
}

// ---------- t = bf16( dis * (x @ W) ): register-tiled fp32 GEMM ----------

__global__ __launch_bounds__(256) void xw_t_gemm_kernel(const float* __restrict__ x, const float* __restrict__ W,
                                                        const float* __restrict__ dis,
                                                        unsigned short* __restrict__ t, int n) {
    __shared__ float xT[D][BM];   // [k][row], 32 KB
    __shared__ float Wl[D][D];    // [k][col], 16 KB
    int tid = threadIdx.x;
    int r0 = blockIdx.x * BM;

    {
        const float4* Wv = (const float4*)W;
        float4* Wd = (float4*)&Wl[0][0];
#pragma unroll
        for (int j = 0; j < 4; ++j) Wd[j * 256 + tid] = Wv[j * 256 + tid];
    }
    {
        int row = tid >> 1;
        int c0 = (tid & 1) * 32;
        int gr = r0 + row;
        if (gr < n) {
            const float4* xv = (const float4*)(x + (size_t)gr * D + c0);
#pragma unroll
            for (int j = 0; j < 8; ++j) {
                float4 v = xv[j];
                int c = c0 + j * 4;
                xT[c + 0][row] = v.x;
                xT[c + 1][row] = v.y;
                xT[c + 2][row] = v.z;
                xT[c + 3][row] = v.w;
            }
        }
    }
    __syncthreads();

    int cg = tid & 15;
    int rg = tid >> 4;
    float acc[8][4];
#pragma unroll
    for (int i = 0; i < 8; ++i)
#pragma unroll
        for (int j = 0; j < 4; ++j) acc[i][j] = 0.0f;

#pragma unroll 8
    for (int k = 0; k < D; ++k) {
        float4 xa = *(const float4*)&xT[k][rg * 8];
        float4 xb = *(const float4*)&xT[k][rg * 8 + 4];
        float4 wv = *(const float4*)&Wl[k][cg * 4];
        float xr[8] = {xa.x, xa.y, xa.z, xa.w, xb.x, xb.y, xb.z, xb.w};
        float wr[4] = {wv.x, wv.y, wv.z, wv.w};
#pragma unroll
        for (int i = 0; i < 8; ++i)
#pragma unroll
            for (int j = 0; j < 4; ++j) acc[i][j] += xr[i] * wr[j];
    }

#pragma unroll
    for (int i = 0; i < 8; ++i) {
        int gr = r0 + rg * 8 + i;
        if (gr < n) {
            float dsc = dis[gr];
            ushort4 o;
            o.x = f2bf(acc[i][0] * dsc); o.y = f2bf(acc[i][1] * dsc);
            o.z = f2bf(acc[i][2] * dsc); o.w = f2bf(acc[i][3] * dsc);
            *(ushort4*)(t + (size_t)gr * D + cg * 4) = o;
        }
    }
}

// ---------- gather: one wave per node, 8-edge subgroups, bf16 rows, 4-deep MLP ----------

__device__ inline void add8(float* acc, uint4 u) {
    acc[0] += __uint_as_float(u.x << 16);
    acc[1] += __uint_as_float(u.x & 0xFFFF0000u);
    acc[2] += __uint_as_float(u.y << 16);
    acc[3] += __uint_as_float(u.y & 0xFFFF0000u);
    acc[4] += __uint_as_float(u.z << 16);
    acc[5] += __uint_as_float(u.z & 0xFFFF0000u);
    acc[6] += __uint_as_float(u.w << 16);
    acc[7] += __uint_as_float(u.w & 0xFFFF0000u);
}

__global__ __launch_bounds__(256) void gather8_kernel(const int* __restrict__ off, const int* __restrict__ end,
                                                      const int* __restrict__ srcs,
                                                      const unsigned short* __restrict__ t,
                                                      const float* __restrict__ dis, const float* __restrict__ b,
                                                      float* __restrict__ out, int n) {
    int c    = blockIdx.x * 4 + (threadIdx.x >> 6);
    int lane = threadIdx.x & 63;
    if (c >= n) return;
    int e8 = lane >> 3;   // edge subgroup 0..7
    int d8 = lane & 7;    // 16B chunk of row
    int j0 = off[c];
    int jend = end[c];

    float acc[8];
#pragma unroll
    for (int q = 0; q < 8; ++q) acc[q] = 0.0f;

    if (e8 == 0) {  // self-loop term
        uint4 u = *(const uint4*)(t + (size_t)c * D + d8 * 8);
        add8(acc, u);
    }

    for (int jb = j0; jb < jend; jb += 64) {
        int m = jend - jb; if (m > 64) m = 64;
        int sv = (jb + lane < jend) ? srcs[jb + lane] : 0;
        int k = 0;
        for (; k + 32 <= m; k += 32) {   // 4 independent loads in flight
            int r0 = __shfl(sv, k + e8);
            int r1 = __shfl(sv, k + 8 + e8);
            int r2 = __shfl(sv, k + 16 + e8);
            int r3 = __shfl(sv, k + 24 + e8);
            uint4 u0 = *(const uint4*)(t + (size_t)r0 * D + d8 * 8);
            uint4 u1 = *(const uint4*)(t + (size_t)r1 * D + d8 * 8);
            uint4 u2 = *(const uint4*)(t + (size_t)r2 * D + d8 * 8);
            uint4 u3 = *(const uint4*)(t + (size_t)r3 * D + d8 * 8);
            add8(acc, u0); add8(acc, u1); add8(acc, u2); add8(acc, u3);
        }
        for (; k + 16 <= m; k += 16) {
            int r0 = __shfl(sv, k + e8);
            int r1 = __shfl(sv, k + 8 + e8);
            uint4 u0 = *(const uint4*)(t + (size_t)r0 * D + d8 * 8);
            uint4 u1 = *(const uint4*)(t + (size_t)r1 * D + d8 * 8);
            add8(acc, u0); add8(acc, u1);
        }
        for (; k < m; k += 8) {
            int idx = k + e8;
            int r = __shfl(sv, idx);
            if (idx < m) {
                uint4 u = *(const uint4*)(t + (size_t)r * D + d8 * 8);
                add8(acc, u);
            }
        }
    }

#pragma unroll
    for (int s = 8; s < 64; s <<= 1)
#pragma unroll
        for (int q = 0; q < 8; ++q) acc[q] += __shfl_xor(acc[q], s);

    if (e8 == 0) {
        float dsc = dis[c];
        float* op = out + (size_t)c * D + d8 * 8;
        const float* bp = b + d8 * 8;
        float4 o0, o1;
        o0.x = bp[0] + dsc * acc[0]; o0.y = bp[1] + dsc * acc[1];
        o0.z = bp[2] + dsc * acc[2]; o0.w = bp[3] + dsc * acc[3];
        o1.x = bp[4] + dsc * acc[4]; o1.y = bp[5] + dsc * acc[5];
        o1.z = bp[6] + dsc * acc[6]; o1.w = bp[7] + dsc * acc[7];
        *(float4*)op = o0;
        *(float4*)(op + 4) = o1;
    }
}

// ---------- mid fallback: flat hist/scan/fill CSR + gather8 ----------

__global__ __launch_bounds__(256) void cnt_init_kernel(int* __restrict__ cnt, int n) {
    int i = blockIdx.x * 256 + threadIdx.x;
    if (i < n) cnt[i] = 0;
}
__global__ __launch_bounds__(256) void hist_kernel(const int* __restrict__ col, int* __restrict__ cnt, int e) {
    int i = blockIdx.x * 256 + threadIdx.x;
    if (i < e) atomicAdd(&cnt[col[i]], 1);
}
__global__ __launch_bounds__(1024) void scan1_kernel(const int* __restrict__ cnt, float* __restrict__ dis,
                                                     int* __restrict__ off, int* __restrict__ bsum, int n) {
    __shared__ int s[1024];
    int tid = threadIdx.x;
    int i = blockIdx.x * 1024 + tid;
    int v = (i < n) ? cnt[i] : 0;
    if (i < n) dis[i] = rsqrtf((float)(v + 1));
    s[tid] = v;
    __syncthreads();
#pragma unroll
    for (int d = 1; d < 1024; d <<= 1) {
        int add = (tid >= d) ? s[tid - d] : 0;
        __syncthreads();
        s[tid] += add;
        __syncthreads();
    }
    int incl = s[tid];
    if (i < n) off[i] = incl - v;
    if (tid == 1023) bsum[blockIdx.x] = incl;
}
__global__ __launch_bounds__(1024) void scan2_kernel(int* __restrict__ bsum, int nb) {
    __shared__ int s[1024];
    int tid = threadIdx.x;
    int v = (tid < nb) ? bsum[tid] : 0;
    s[tid] = v;
    __syncthreads();
#pragma unroll
    for (int d = 1; d < 1024; d <<= 1) {
        int add = (tid >= d) ? s[tid - d] : 0;
        __syncthreads();
        s[tid] += add;
        __syncthreads();
    }
    if (tid < nb) bsum[tid] = s[tid] - v;
}
__global__ __launch_bounds__(1024) void scan3_kernel(int* __restrict__ off, const int* __restrict__ bsum,
                                                     int* __restrict__ cur, int n) {
    int i = blockIdx.x * 1024 + threadIdx.x;
    if (i < n) {
        int o = off[i] + bsum[blockIdx.x];
        off[i] = o;
        cur[i] = o;
    }
}
__global__ __launch_bounds__(256) void fill_kernel(const int* __restrict__ row, const int* __restrict__ col,
                                                   int* __restrict__ cur, int* __restrict__ srcs, int e) {
    int i = blockIdx.x * 256 + threadIdx.x;
    if (i < e) {
        int pos = atomicAdd(&cur[col[i]], 1);
        srcs[pos] = row[i];
    }
}

// ---------- last fallback: atomic scatter ----------

__global__ __launch_bounds__(256) void deg_init_kernel(float* __restrict__ deg, int n) {
    int i = blockIdx.x * 256 + threadIdx.x;
    if (i < n) deg[i] = 1.0f;
}
__global__ __launch_bounds__(256) void deg_count_kernel(const int* __restrict__ col, float* __restrict__ deg, int e) {
    int i = blockIdx.x * 256 + threadIdx.x;
    if (i < e) atomicAdd(&deg[col[i]], 1.0f);
}
__global__ __launch_bounds__(256) void deg_rsqrt_kernel(float* __restrict__ deg, int n) {
    int i = blockIdx.x * 256 + threadIdx.x;
    if (i < n) deg[i] = rsqrtf(deg[i]);
}
__global__ __launch_bounds__(256) void xw_kernel(const float* __restrict__ x, const float* __restrict__ W,
                                                 float* __restrict__ xw, int n) {
    __shared__ float Wl[D * D];
    int tid = threadIdx.x;
    for (int i = tid; i < D * D; i += 256) Wl[i] = W[i];
    __syncthreads();
    int lane = tid & 63;
    int row  = blockIdx.x * 4 + (tid >> 6);
    if (row >= n) return;
    float xv = x[(size_t)row * D + lane];
    float acc = 0.0f;
#pragma unroll
    for (int k = 0; k < D; ++k) acc += __shfl(xv, k) * Wl[k * D + lane];
    xw[(size_t)row * D + lane] = acc;
}
__global__ __launch_bounds__(256) void out_init_kernel(const float* __restrict__ xw, const float* __restrict__ dis,
                                                       const float* __restrict__ b, float* __restrict__ out, int n) {
    int i = blockIdx.x * 256 + threadIdx.x;
    if (i < n * D) {
        int node = i >> 6;
        float d = dis[node];
        out[i] = b[i & 63] + d * d * xw[i];
    }
}
__global__ __launch_bounds__(256) void scatter_kernel(const int* __restrict__ row, const int* __restrict__ col,
                                                      const float* __restrict__ dis, const float* __restrict__ xw,
                                                      float* __restrict__ out, int e) {
    int idx  = blockIdx.x * 4 + (threadIdx.x >> 6);
    int lane = threadIdx.x & 63;
    if (idx >= e) return;
    int r = row[idx], c = col[idx];
    float w = dis[r] * dis[c];
    atomicAdd(&out[(size_t)c * D + lane], w * xw[(size_t)r * D + lane]);
}

// ---------- launch ----------

extern "C" void kernel_launch(void* const* d_in, const int* in_sizes, int n_in,
                              void* d_out, int out_size, void* d_ws, size_t ws_size,
                              hipStream_t stream) {
    const float* x  = (const float*)d_in[0];
    const int*   ei = (const int*)d_in[1];
    const float* W  = (const float*)d_in[2];
    const float* b  = (const float*)d_in[3];
    float*       out = (float*)d_out;

    int n = in_sizes[0] / D;   // 100000
    int e = in_sizes[1] / 2;   // 1600000
    const int* row = ei;
    const int* col = ei + e;

    size_t nA = ((size_t)n + 255) & ~(size_t)255;
    int nb = (n + BCOLS - 1) >> BSH;

    // fast: bcnt[1024] bcur[1024] base[1056] off[nA] end[nA] (int) | dis[nA] (f32) | t[nA*D] (bf16) | binned[e] srcs[e]
    size_t fast_needed = (size_t)(1024 + 1024 + 1056) * 4 + 2 * nA * 4 + nA * 4 + nA * D * 2 + 2 * (size_t)e * 4;
    size_t mid_needed  = (3 * nA + 1024) * 4 + nA * 4 + nA * D * 2 + (size_t)e * 4;

    if (n <= 131072 && nb <= MAXNB && ws_size >= fast_needed) {
        int*   bcnt   = (int*)d_ws;
        int*   bcur   = bcnt + 1024;
        int*   base   = bcur + 1024;
        int*   off    = base + 1056;
        int*   end    = off + nA;
        float* dis    = (float*)(end + nA);
        unsigned short* t = (unsigned short*)(dis + nA);
        unsigned int* binned = (unsigned int*)(t + nA * D);
        int*   srcs   = (int*)(binned + e);

        int chunk = (e + NBLK3 - 1) / NBLK3;

        hipMemsetAsync(bcnt, 0, 2048 * 4, stream);  // bcnt + bcur
        bhist_kernel<<<256, 256, 0, stream>>>(col, bcnt, e, nb);
        bscatter_kernel<<<NBLK3, 256, 0, stream>>>(row, col, bcnt, bcur, base, binned, e, nb, chunk);
        bucket_build_kernel<<<nb, 256, 0, stream>>>(base, binned, off, end, dis, srcs, n);
        xw_t_gemm_kernel<<<(n + BM - 1) / BM, 256, 0, stream>>>(x, W, dis, t, n);
        gather8_kernel<<<(n + 3) / 4, 256, 0, stream>>>(off, end, srcs, t, dis, b, out, n);
    } else if (ws_size >= mid_needed) {
        int*   cnt  = (int*)d_ws;
        int*   off  = cnt + nA;
        int*   cur  = off + nA;
        int*   bsum = cur + nA;
        float* dis  = (float*)(bsum + 1024);
        unsigned short* t = (unsigned short*)(dis + nA);
        int*   srcs = (int*)(t + nA * D);

        int nblk = (n + 1023) / 1024;
        cnt_init_kernel<<<(n + 255) / 256, 256, 0, stream>>>(cnt, n);
        hist_kernel<<<(e + 255) / 256, 256, 0, stream>>>(col, cnt, e);
        scan1_kernel<<<nblk, 1024, 0, stream>>>(cnt, dis, off, bsum, n);
        scan2_kernel<<<1, 1024, 0, stream>>>(bsum, nblk);
        scan3_kernel<<<nblk, 1024, 0, stream>>>(off, bsum, cur, n);
        xw_t_gemm_kernel<<<(n + BM - 1) / BM, 256, 0, stream>>>(x, W, dis, t, n);
        fill_kernel<<<(e + 255) / 256, 256, 0, stream>>>(row, col, cur, srcs, e);
        gather8_kernel<<<(n + 3) / 4, 256, 0, stream>>>(off, cur, srcs, t, dis, b, out, n);
    } else {
        float* deg = (float*)d_ws;
        float* xw  = deg + nA;
        deg_init_kernel<<<(n + 255) / 256, 256, 0, stream>>>(deg, n);
        deg_count_kernel<<<(e + 255) / 256, 256, 0, stream>>>(col, deg, e);
        deg_rsqrt_kernel<<<(n + 255) / 256, 256, 0, stream>>>(deg, n);
        xw_kernel<<<(n + 3) / 4, 256, 0, stream>>>(x, W, xw, n);
        out_init_kernel<<<((size_t)n * D + 255) / 256, 256, 0, stream>>>(xw, deg, b, out, n);
        scatter_kernel<<<(e + 3) / 4, 256, 0, stream>>>(row, col, deg, xw, out, e);
    }
}